// Round 8
// baseline (374.684 us; speedup 1.0000x reference)
//
#include <hip/hip_runtime.h>

// ScaledDotProductAttention: B=4, NQ=NK=2048, D_MODEL=D_K=D_V=1024, H=16, HD=64.
// Full bf16-MFMA pipeline (fp32 accumulate everywhere):
//  1) transpose_cast_w : W* fp32 [K][N] -> bf16 [N][K]   (B^T layout for MFMA B-frags)
//  2) proj_kernel      : Q/K/V projections, 128x256 tile, BK=64, 512 thr.
//                        R13: LATENCY-MLP theory. R3/R9/R10/R11/R12 all ~150-166us
//                        across five sync/tile structures; common factor = 24KB stage
//                        quantum -> burst-drain duty cycle keeps avg outstanding DMA
//                        ~8 B/cy/CU (15% of L2 BW, 13% MfmaUtil: latency-bound).
//                        Fix: 64KB stages (BK=64), 16 K-steps, 2x64KB LDS dbuf,
//                        asm ds_reads (only drain = post-process __syncthreads).
//  3) attn_kernel      : transposed-S flash attention; R13: KV tile 128 keys
//                        (32KB stages, 16 tiles), s-subtile loop 0..3.
//  4) out_kernel       : O @ Wo + bo; R13: BK=64 (32KB stages), dbuf, asm reads.
// Workspace: 72 MiB total (offsets below, unchanged).

#define DM    1024
#define NSEQ  2048
#define HEADS 16
#define HD    64

typedef float floatx4 __attribute__((ext_vector_type(4)));
typedef short s16x4   __attribute__((ext_vector_type(4)));
typedef short s16x8   __attribute__((ext_vector_type(8)));
typedef unsigned int u32x4 __attribute__((ext_vector_type(4)));

static __device__ __forceinline__ floatx4 mfma_bf16(s16x8 a, s16x8 b, floatx4 c) {
  return __builtin_amdgcn_mfma_f32_16x16x32_bf16(a, b, c, 0, 0, 0);
}

// Async global->LDS DMA, 16B per lane: dest = wave-uniform base + lane*16,
// source = per-lane global address.
static __device__ __forceinline__ void gload_lds16(const void* g, void* l) {
  __builtin_amdgcn_global_load_lds(
      (const __attribute__((address_space(1))) unsigned*)g,
      (__attribute__((address_space(3))) unsigned*)l, 16, 0, 0);
}

// 32-bit LDS byte address from a generic pointer into __shared__.
static __device__ __forceinline__ unsigned lds_addr(const void* p) {
  return (unsigned)(unsigned long long)p;
}

// Inline-asm ds_read_b128 (opaque to alias analysis -> no compiler-inserted
// vmcnt(0) drain before it; caller fences per rule #18).
static __device__ __forceinline__ s16x8 ds_read_b128a(unsigned byteaddr) {
  s16x8 r;
  asm volatile("ds_read_b128 %0, %1" : "=v"(r) : "v"(byteaddr));
  return r;
}

#define WAIT_LGKM0() \
  { asm volatile("s_waitcnt lgkmcnt(0)" ::: "memory"); __builtin_amdgcn_sched_barrier(0); }

// fp32 -> bf16 round-to-nearest-even (bit trick; inputs are finite)
static __device__ __forceinline__ short f2bf(float f) {
  unsigned u = __builtin_bit_cast(unsigned, f);
  u += 0x7FFFu + ((u >> 16) & 1u);
  return (short)(u >> 16);
}

// Packed fp32 pair -> 2 bf16 (RNE, same result as f2bf) in one VALU op.
static __device__ __forceinline__ unsigned cvtpk_bf16(float lo, float hi) {
  unsigned r;
  asm("v_cvt_pk_bf16_f32 %0, %1, %2" : "=v"(r) : "v"(lo), "v"(hi));
  return r;
}

// Pack 2 fp32 -> 2 bf16 in one u32 (round-half-up: +0x8000, keep high halves).
static __device__ __forceinline__ unsigned pack2_bf16(float a, float b) {
  unsigned ua = __builtin_bit_cast(unsigned, a) + 0x8000u;
  unsigned ub = __builtin_bit_cast(unsigned, b) + 0x8000u;
#if __has_builtin(__builtin_amdgcn_perm)
  return __builtin_amdgcn_perm(ub, ua, 0x07060302u);  // lo=hi16(ua), hi=hi16(ub)
#else
  return (ub & 0xffff0000u) | (ua >> 16);
#endif
}

// ---------------------------------------------------------------------------
// 1) Weight transpose + cast: W [1024 k][1024 n] fp32 -> Wt [n][k] bf16
__global__ __launch_bounds__(256) void transpose_cast_w(
    const float* __restrict__ W0, const float* __restrict__ W1,
    const float* __restrict__ W2, const float* __restrict__ W3,
    short* __restrict__ T0, short* __restrict__ T1,
    short* __restrict__ T2, short* __restrict__ T3) {
  __shared__ float tile[32][33];
  const float* W = blockIdx.z == 0 ? W0 : blockIdx.z == 1 ? W1 : blockIdx.z == 2 ? W2 : W3;
  short*       T = blockIdx.z == 0 ? T0 : blockIdx.z == 1 ? T1 : blockIdx.z == 2 ? T2 : T3;
  const int bx = blockIdx.x * 32;  // n-offset
  const int by = blockIdx.y * 32;  // k-offset
  const int tx = threadIdx.x, ty = threadIdx.y;
  for (int i = 0; i < 4; i++)
    tile[ty + i * 8][tx] = W[(long)(by + ty + i * 8) * DM + bx + tx];
  __syncthreads();
  for (int i = 0; i < 4; i++)
    T[(long)(bx + ty + i * 8) * DM + by + tx] = f2bf(tile[tx][ty + i * 8]);
}

// ---------------------------------------------------------------------------
// 2) Projection GEMM: C[8192x1024] = A(fp32) @ W.  128x256 tile, BK=64, 512 thr.
//    Per 64KiB buffer:
//      A fp32, 32 groups x 1KiB at byte ga*1024; ga = g16*4 + kk*2 + h:
//        chunk l = A[row0+g16*16+(l&15)][k0 + kk*32 + (l>>4)*8 + h*4 ..+4]
//      B bf16, 32 groups x 1KiB at byte 32768 + gb*1024; gb = g16c*2 + kk:
//        chunk l = Bt[col0+g16c*16+(l&15)][k0 + kk*32 + (l>>4)*8 ..+8]
//    Stage = 8 gload_lds per wave (4 A + 4 B). Consumer (wave wm=w>>2, wn=w&3):
//    per kk: af[mi] from groups (wm*4+mi, kk, h=0/1) via cvt_pk; bfr[ni] from
//    (wn*4+ni, kk). All reads group_base + l*16: linear, conflict-free.
//    z=0: queries->Qh (PRE-SCALED log2e/sqrt(1024)), 1: keys->Kh, 2: values->Vt.
__global__ __launch_bounds__(512, 2) void proj_kernel(
    const float* __restrict__ Aq, const float* __restrict__ Ak, const float* __restrict__ Av,
    const short* __restrict__ BtQ, const short* __restrict__ BtK, const short* __restrict__ BtV,
    short* __restrict__ Qh, short* __restrict__ Kh, short* __restrict__ Vt) {
  __shared__ short lds[2 * 32768];  // 2 x 64 KiB (A 32K fp32 + B 32K bf16)
  const int z = blockIdx.z;
  const float* A  = z == 0 ? Aq  : z == 1 ? Ak  : Av;
  const short* Bt = z == 0 ? BtQ : z == 1 ? BtK : BtV;
  const int t = threadIdx.x;
  const int w = t >> 6, l = t & 63, quad = l >> 4, lm = l & 15;
  const int wm = w >> 2, wn = w & 3;  // 2 row-waves x 4 col-waves
  const int row0 = blockIdx.x * 128, col0 = blockIdx.y * 256;

  floatx4 acc[4][4];
  for (int mi = 0; mi < 4; mi++)
    for (int ni = 0; ni < 4; ni++) acc[mi][ni] = (floatx4){0.f, 0.f, 0.f, 0.f};

  // Stage the 64-k tile at k0 into buffer buf. Wave w: A groups w*4..+3,
  // B groups w*4..+3 (8 gload_lds per wave).
  auto stage = [&](int k0, int buf) __attribute__((always_inline)) {
    short* base = lds + buf * 32768;
#pragma unroll
    for (int i = 0; i < 4; i++) {
      int ga = w * 4 + i, g16 = ga >> 2, kk = (ga >> 1) & 1, h = ga & 1;
      const float* src =
          A + (long)(row0 + g16 * 16 + lm) * DM + k0 + kk * 32 + quad * 8 + h * 4;
      gload_lds16(src, base + ga * 512);
    }
#pragma unroll
    for (int i = 0; i < 4; i++) {
      int gb = w * 4 + i, g16c = gb >> 1, kk = gb & 1;
      const short* src =
          Bt + (long)(col0 + g16c * 16 + lm) * DM + k0 + kk * 32 + quad * 8;
      gload_lds16(src, base + 16384 + gb * 512);
    }
  };

  const unsigned lds0 = lds_addr(lds);
  auto process = [&](int buf) __attribute__((always_inline)) {
    const unsigned lbase = lds0 + buf * 65536;
#pragma unroll
    for (int kk = 0; kk < 2; kk++) {
      floatx4 alo[4], ahi[4];
      s16x8 bfr[4];
#pragma unroll
      for (int mi = 0; mi < 4; mi++) {
        unsigned ga0 = ((wm * 4 + mi) * 4 + kk * 2) * 1024;
        alo[mi] = __builtin_bit_cast(floatx4, ds_read_b128a(lbase + ga0 + l * 16));
        ahi[mi] = __builtin_bit_cast(floatx4, ds_read_b128a(lbase + ga0 + 1024 + l * 16));
      }
#pragma unroll
      for (int ni = 0; ni < 4; ni++) {
        unsigned gb0 = 32768u + ((wn * 4 + ni) * 2 + kk) * 1024;
        bfr[ni] = ds_read_b128a(lbase + gb0 + l * 16);
      }
      WAIT_LGKM0();  // asm reads done; MFMAs can't hoist above (rule #18)
      s16x8 af[4];
#pragma unroll
      for (int mi = 0; mi < 4; mi++) {
        u32x4 p = {cvtpk_bf16(alo[mi][0], alo[mi][1]), cvtpk_bf16(alo[mi][2], alo[mi][3]),
                   cvtpk_bf16(ahi[mi][0], ahi[mi][1]), cvtpk_bf16(ahi[mi][2], ahi[mi][3])};
        af[mi] = __builtin_bit_cast(s16x8, p);
      }
      __builtin_amdgcn_s_setprio(1);
#pragma unroll
      for (int mi = 0; mi < 4; mi++)
#pragma unroll
        for (int ni = 0; ni < 4; ni++)
          acc[mi][ni] = mfma_bf16(af[mi], bfr[ni], acc[mi][ni]);
      __builtin_amdgcn_s_setprio(0);
    }
  };

  stage(0, 0);
  __syncthreads();  // tile 0 ready
  int cur = 0;
  for (int tt = 0; tt < 16; ++tt) {
    if (tt + 1 < 16) stage((tt + 1) * 64, cur ^ 1);  // issue DMA, then compute
    process(cur);
    __syncthreads();  // drain (mostly overlapped by process) + publish
    cur ^= 1;
  }

  const int rowbase = row0 + wm * 64;  // multiple of 64 -> single b per wave
  const int colbase = col0 + wn * 64;  // multiple of 64 -> single head per wave
  const int b = rowbase >> 11;
  const int h = colbase >> 6;
  const int rloc = rowbase & 2047;
  if (z < 2) {
    short* Out = z == 0 ? Qh : Kh;
    // Fold softmax scale * log2(e) into Q so attn uses exp2 with no multiply.
    const float osc = z == 0 ? 0.0450842200277801f : 1.0f;
    long base = ((long)(b * HEADS + h)) * NSEQ * HD;
    for (int mi = 0; mi < 4; mi++)
      for (int r = 0; r < 4; r++) {
        int q = rloc + mi * 16 + quad * 4 + r;
        long rowoff = base + (long)q * HD + lm;
        for (int ni = 0; ni < 4; ni++)
          Out[rowoff + ni * 16] = f2bf(acc[mi][ni][r] * osc);
      }
  } else {
    // Vt with per-32-key interleave: key kloc=(j*16+quad*4+r) within its 32-group
    // is stored at position quad*8 + j*4 + r, so attn reads one 16B chunk per
    // (d-row, quad) covering a full K=32 logical-k fragment.
    long base = ((long)(b * HEADS + h)) * HD * NSEQ;
    for (int mi = 0; mi < 4; mi++)
      for (int r = 0; r < 4; r++) {
        int kcol = rloc + (mi >> 1) * 32 + quad * 8 + (mi & 1) * 4 + r;
        for (int ni = 0; ni < 4; ni++)
          Vt[base + (long)(ni * 16 + lm) * NSEQ + kcol] = f2bf(acc[mi][ni][r]);
      }
  }
}

// ---------------------------------------------------------------------------
// 3) Transposed-S flash attention. Grid (bh=64, qy=16) -> XCD = bh%8 (L2 local).
//    4 waves/block, wave = 32 q-rows (2x16). R13: 128-key tiles (32KB stages),
//    16 tiles; K groups 0..15 (s=g>>2, j, c), V groups 16..31 (s, n); 8 gloads
//    per wave per tile; subtile loop s=0..3. (256,2): no spill (R8).
__global__ __launch_bounds__(256, 2) void attn_kernel(
    const short* __restrict__ Qh, const short* __restrict__ Kh,
    const short* __restrict__ Vt, short* __restrict__ Obf) {
  __shared__ short lds[2 * 16384];  // 2 x 32KiB tile buffers; epilogue reuses buf0
  const int t = threadIdx.x;
  const int w = t >> 6, l = t & 63, quad = l >> 4, lm = l & 15;
  const int bh = blockIdx.x;    // b*16+h  (grid-x => XCD = bh%8: L2 locality)
  const int qtile = blockIdx.y * 128 + w * 32;
  const short* Qp = Qh + (long)bh * NSEQ * HD;
  const short* Kp = Kh + (long)bh * NSEQ * HD;
  const short* Vp = Vt + (long)bh * HD * NSEQ;

  s16x8 aq[2][2];  // Q-frags; serve as MFMA *B* operand for S^T (layout identical)
#pragma unroll
  for (int qi = 0; qi < 2; qi++)
#pragma unroll
    for (int c = 0; c < 2; c++)
      aq[qi][c] = *(const s16x8*)(Qp + (long)(qtile + qi * 16 + lm) * HD + c * 32 + quad * 8);

  floatx4 acc[2][4];  // O^T, C-layout: d = n*16+quad*4+reg, q = lm
  float lsum[2] = {0.f, 0.f};
#pragma unroll
  for (int qi = 0; qi < 2; qi++)
#pragma unroll
    for (int n = 0; n < 4; n++) acc[qi][n] = (floatx4){0.f, 0.f, 0.f, 0.f};

  // Stage the 128-key tile at kt into buffer buf. Wave w stages groups 8w..8w+7.
  auto stage = [&](int kt, int buf) __attribute__((always_inline)) {
    short* base = lds + buf * 16384;
#pragma unroll
    for (int i = 0; i < 8; i++) {
      int g = w * 8 + i;
      const short* src;
      if (w < 2) {  // K groups 0..15
        int s = g >> 2, j = (g >> 1) & 1, c = g & 1;
        src = Kp + (long)(kt + s * 32 + j * 16 + lm) * HD + c * 32 + quad * 8;
      } else {      // V groups 16..31
        int gg = g & 15;
        int s = gg >> 2, n = gg & 3;
        src = Vp + (long)(n * 16 + lm) * NSEQ + kt + s * 32 + quad * 8;
      }
      gload_lds16(src, base + g * 512);
    }
  };

  // Process one 32-key subtile (s = 0..3) from tile buffer Lb.
  auto process = [&](const short* Lb, int s) __attribute__((always_inline)) {
    s16x8 bk[2][2];
#pragma unroll
    for (int j = 0; j < 2; j++)
#pragma unroll
      for (int c = 0; c < 2; c++)
        bk[j][c] = *(const s16x8*)(Lb + ((s * 4 + j * 2 + c) * 64 + l) * 8);
    s16x8 vraw[4];
#pragma unroll
    for (int n = 0; n < 4; n++)
      vraw[n] = *(const s16x8*)(Lb + ((16 + s * 4 + n) * 64 + l) * 8);
#pragma unroll
    for (int qi = 0; qi < 2; qi++) {
      floatx4 sT[2];
      sT[0] = (floatx4){0.f, 0.f, 0.f, 0.f};
      sT[1] = (floatx4){0.f, 0.f, 0.f, 0.f};
      __builtin_amdgcn_s_setprio(1);
#pragma unroll
      for (int c = 0; c < 2; c++) {
        sT[0] = mfma_bf16(bk[0][c], aq[qi][c], sT[0]);
        sT[1] = mfma_bf16(bk[1][c], aq[qi][c], sT[1]);
      }
      __builtin_amdgcn_s_setprio(0);
      float p0 = __builtin_amdgcn_exp2f(sT[0][0]);
      float p1 = __builtin_amdgcn_exp2f(sT[0][1]);
      float p2 = __builtin_amdgcn_exp2f(sT[0][2]);
      float p3 = __builtin_amdgcn_exp2f(sT[0][3]);
      float p4 = __builtin_amdgcn_exp2f(sT[1][0]);
      float p5 = __builtin_amdgcn_exp2f(sT[1][1]);
      float p6 = __builtin_amdgcn_exp2f(sT[1][2]);
      float p7 = __builtin_amdgcn_exp2f(sT[1][3]);
      lsum[qi] += ((p0 + p1) + (p2 + p3)) + ((p4 + p5) + (p6 + p7));
      u32x4 pw = {pack2_bf16(p0, p1), pack2_bf16(p2, p3),
                  pack2_bf16(p4, p5), pack2_bf16(p6, p7)};
      s16x8 pcat = __builtin_bit_cast(s16x8, pw);
      __builtin_amdgcn_s_setprio(1);
#pragma unroll
      for (int n = 0; n < 4; n++)
        acc[qi][n] = mfma_bf16(vraw[n], pcat, acc[qi][n]);
      __builtin_amdgcn_s_setprio(0);
    }
  };

  stage(0, 0);
  __syncthreads();  // tile 0 ready
  int cur = 0;
  for (int kt = 0; kt < NSEQ; kt += 128) {
    if (kt + 128 < NSEQ) stage(kt + 128, cur ^ 1);  // issue DMA, then compute
    const short* Lb = lds + cur * 16384;
    process(Lb, 0);
    process(Lb, 1);
    process(Lb, 2);
    process(Lb, 3);
    __syncthreads();  // drain (hidden under process) + cross-wave visibility
    cur ^= 1;
  }

  // lsum is per-lane over this lane's keys; full row sum = reduce across quads.
  const int b = bh >> 4, h = bh & 15;
  short* Ow = lds + w * 1152;  // reuse buf0 (final tile read buf1; disjoint)
  const int erow = l >> 2, ecg = l & 3;  // epilogue read/store mapping
#pragma unroll
  for (int qi = 0; qi < 2; qi++) {
    float ls = lsum[qi];
    ls += __shfl_xor(ls, 16);
    ls += __shfl_xor(ls, 32);
    float rl = 1.0f / ls;  // row sum for q = lm (same for all regs)
#pragma unroll
    for (int n = 0; n < 4; n++)
#pragma unroll
      for (int r = 0; r < 4; r++)
        Ow[lm * 72 + n * 16 + quad * 4 + r] = f2bf(acc[qi][n][r] * rl);
    // read back row-major (same wave; compiler inserts lgkmcnt wait), store coalesced
    s16x8 o0 = *(const s16x8*)(Ow + erow * 72 + ecg * 16);
    s16x8 o1 = *(const s16x8*)(Ow + erow * 72 + ecg * 16 + 8);
    long gaddr = ((long)(b * NSEQ + qtile + qi * 16 + erow)) * DM + h * HD + ecg * 16;
    *(s16x8*)(Obf + gaddr) = o0;
    *(s16x8*)(Obf + gaddr + 8) = o1;
  }
}

// ---------------------------------------------------------------------------
// 4) Output GEMM: d_out = Obf(bf16) @ WoT + bo, fp32 out. 128x128, BK=64.
//    Per 32KiB buffer: A 16 groups x 1KiB (ga = g16*2+kk) at byte ga*1024;
//    B 16 groups at byte 16384 + gb*1024. 8 gloads/wave/stage. Asm ds_reads,
//    drain at post-process __syncthreads only.
__global__ __launch_bounds__(256, 2) void out_kernel(
    const short* __restrict__ Ab, const short* __restrict__ Bt,
    const float* __restrict__ bias, float* __restrict__ Out) {
  __shared__ short lds[2 * 16384];  // 2 x 32 KiB
  const int t = threadIdx.x;
  const int w = t >> 6, l = t & 63, quad = l >> 4, lm = l & 15;
  const int wm = w >> 1, wn = w & 1;
  const int row0 = blockIdx.x * 128, col0 = blockIdx.y * 128;

  floatx4 acc[4][4];
  for (int mi = 0; mi < 4; mi++)
    for (int ni = 0; ni < 4; ni++) acc[mi][ni] = (floatx4){0.f, 0.f, 0.f, 0.f};

  auto stage = [&](int k0, int buf) __attribute__((always_inline)) {
    short* base = lds + buf * 16384;
#pragma unroll
    for (int i = 0; i < 8; i++) {
      int g = w * 8 + i;  // 0..31; wave-uniform branch
      const short* src;
      short* dst;
      if (g < 16) {       // A groups: ga = g16*2+kk
        int g16 = g >> 1, kk = g & 1;
        src = Ab + (long)(row0 + g16 * 16 + lm) * DM + k0 + kk * 32 + quad * 8;
        dst = base + g * 512;
      } else {            // B groups
        int gb = g - 16, g16 = gb >> 1, kk = gb & 1;
        src = Bt + (long)(col0 + g16 * 16 + lm) * DM + k0 + kk * 32 + quad * 8;
        dst = base + 8192 + gb * 512;
      }
      gload_lds16(src, dst);
    }
  };
  const unsigned lds0 = lds_addr(lds);
  auto process = [&](int buf) __attribute__((always_inline)) {
    const unsigned lbase = lds0 + buf * 32768;
#pragma unroll
    for (int kk = 0; kk < 2; kk++) {
      s16x8 af[4], bfr[4];
#pragma unroll
      for (int mi = 0; mi < 4; mi++)
        af[mi] = ds_read_b128a(lbase + ((wm * 4 + mi) * 2 + kk) * 1024 + l * 16);
#pragma unroll
      for (int ni = 0; ni < 4; ni++)
        bfr[ni] = ds_read_b128a(lbase + 16384 + ((wn * 4 + ni) * 2 + kk) * 1024 + l * 16);
      WAIT_LGKM0();
      __builtin_amdgcn_s_setprio(1);
#pragma unroll
      for (int mi = 0; mi < 4; mi++)
#pragma unroll
        for (int ni = 0; ni < 4; ni++)
          acc[mi][ni] = mfma_bf16(af[mi], bfr[ni], acc[mi][ni]);
      __builtin_amdgcn_s_setprio(0);
    }
  };

  stage(0, 0);
  __syncthreads();
  int cur = 0;
  for (int tt = 0; tt < 16; ++tt) {
    if (tt + 1 < 16) stage((tt + 1) * 64, cur ^ 1);
    process(cur);
    __syncthreads();
    cur ^= 1;
  }

  const int rowbase = row0 + wm * 64;
  const int colbase = col0 + wn * 64;
  for (int mi = 0; mi < 4; mi++)
    for (int r = 0; r < 4; r++) {
      int gr = rowbase + mi * 16 + quad * 4 + r;
      for (int ni = 0; ni < 4; ni++) {
        int gc = colbase + ni * 16 + lm;
        Out[(long)gr * DM + gc] = acc[mi][ni][r] + bias[gc];
      }
    }
}

// ---------------------------------------------------------------------------
extern "C" void kernel_launch(void* const* d_in, const int* in_sizes, int n_in,
                              void* d_out, int out_size, void* d_ws, size_t ws_size,
                              hipStream_t stream) {
  (void)in_sizes; (void)n_in; (void)out_size; (void)ws_size;
  const float* queries = (const float*)d_in[0];
  const float* keys    = (const float*)d_in[1];
  const float* values  = (const float*)d_in[2];
  const float* Wq = (const float*)d_in[3];
  const float* Wk = (const float*)d_in[4];
  const float* Wv = (const float*)d_in[5];
  const float* Wo = (const float*)d_in[6];
  const float* bo = (const float*)d_in[7];
  float* out = (float*)d_out;

  char* ws = (char*)d_ws;
  const size_t MB = 1024 * 1024;
  short* WqT = (short*)(ws + 0 * MB);   // 2 MiB each
  short* WkT = (short*)(ws + 2 * MB);
  short* WvT = (short*)(ws + 4 * MB);
  short* WoT = (short*)(ws + 6 * MB);
  short* Qh  = (short*)(ws + 8 * MB);   // [B,H,2048,64] bf16 = 16 MiB
  short* Kh  = (short*)(ws + 24 * MB);  // 16 MiB
  short* Vt  = (short*)(ws + 40 * MB);  // [B,H,64,2048] bf16 (interleaved cols) = 16 MiB
  short* Obf = (short*)(ws + 56 * MB);  // [8192,1024] bf16 = 16 MiB  (total 72 MiB)

  transpose_cast_w<<<dim3(32, 32, 4), dim3(32, 8), 0, stream>>>(
      Wq, Wk, Wv, Wo, WqT, WkT, WvT, WoT);
  proj_kernel<<<dim3(64, 4, 3), 512, 0, stream>>>(
      queries, keys, values, WqT, WkT, WvT, Qh, Kh, Vt);
  attn_kernel<<<dim3(64, 16), 256, 0, stream>>>(Qh, Kh, Vt, Obf);
  out_kernel<<<dim3(64, 8), 256, 0, stream>>>(Obf, WoT, bo, out);
}

// Round 9
// 318.537 us; speedup vs baseline: 1.1763x; 1.1763x over previous
//
#include <hip/hip_runtime.h>

// ScaledDotProductAttention: B=4, NQ=NK=2048, D_MODEL=D_K=D_V=1024, H=16, HD=64.
// R14 (coalesced-staging rewrite). ROOT CAUSE of the 148-166us proj invariance
// across R3/R9/R10/R11/R12/R13: fragment-major PER-LANE SOURCE addresses put
// lanes 0-15 on rows 4KB apart -> every staging instruction = 64 scattered 16B
// requests = 64 cache lines @ 16B-used (4x amplification, 4096 line-requests
// per 64KB stage ~= the measured 7400 cy/step). Fix: every staging instruction
// now covers CONTIGUOUS global bytes:
//  1) make_wgroups : W* fp32 [K][N] -> fragment-GROUP layout (1KB groups), so
//                    GEMM B-staging is contiguous gload_lds + linear reads.
//  2) proj_kernel  : 128x256, BK=64, 512thr. B via contiguous gload_lds from
//                    Wg. A (fp32) reg-staged with coalesced 256B row-runs ->
//                    cvt_pk -> ds_write_b128 at XOR-swizzled fragment slot
//                    (l''' = quad*16 ^ ... ; 2-way max both sides). Epilogue
//                    writes Qh row-major and K/V into KVg group layout.
//  3) attn_kernel  : unchanged math; staging now reads KVg contiguously.
//  4) out_kernel   : A (Obf bf16) reg-staged coalesced + swizzled ds_write;
//                    B via contiguous gload_lds from WoG.
// Workspace 72 MiB: Wg 4x2MB | Qh 16MB | KVg 32MB | Obf 16MB.

#define DM    1024
#define NSEQ  2048
#define HEADS 16
#define HD    64

typedef float floatx4 __attribute__((ext_vector_type(4)));
typedef short s16x4   __attribute__((ext_vector_type(4)));
typedef short s16x8   __attribute__((ext_vector_type(8)));
typedef unsigned int u32x4 __attribute__((ext_vector_type(4)));

static __device__ __forceinline__ floatx4 mfma_bf16(s16x8 a, s16x8 b, floatx4 c) {
  return __builtin_amdgcn_mfma_f32_16x16x32_bf16(a, b, c, 0, 0, 0);
}

// Async global->LDS DMA, 16B per lane: dest = wave-uniform base + lane*16,
// source = per-lane global address (contiguous here!).
static __device__ __forceinline__ void gload_lds16(const void* g, void* l) {
  __builtin_amdgcn_global_load_lds(
      (const __attribute__((address_space(1))) unsigned*)g,
      (__attribute__((address_space(3))) unsigned*)l, 16, 0, 0);
}

static __device__ __forceinline__ unsigned lds_addr(const void* p) {
  return (unsigned)(unsigned long long)p;
}

// Inline-asm ds_read_b128 (opaque to alias analysis -> no compiler-inserted
// vmcnt(0) drain; caller fences with lgkmcnt(0)+sched_barrier per rule #18).
static __device__ __forceinline__ s16x8 ds_read_b128a(unsigned byteaddr) {
  s16x8 r;
  asm volatile("ds_read_b128 %0, %1" : "=v"(r) : "v"(byteaddr));
  return r;
}

#define WAIT_LGKM0() \
  { asm volatile("s_waitcnt lgkmcnt(0)" ::: "memory"); __builtin_amdgcn_sched_barrier(0); }

// fp32 -> bf16 round-to-nearest-even (bit trick; inputs are finite)
static __device__ __forceinline__ short f2bf(float f) {
  unsigned u = __builtin_bit_cast(unsigned, f);
  u += 0x7FFFu + ((u >> 16) & 1u);
  return (short)(u >> 16);
}

// Packed fp32 pair -> 2 bf16 (RNE, same result as f2bf) in one VALU op.
static __device__ __forceinline__ unsigned cvtpk_bf16(float lo, float hi) {
  unsigned r;
  asm("v_cvt_pk_bf16_f32 %0, %1, %2" : "=v"(r) : "v"(lo), "v"(hi));
  return r;
}

// Pack 2 fp32 -> 2 bf16 in one u32 (round-half-up; attn P-values only).
static __device__ __forceinline__ unsigned pack2_bf16(float a, float b) {
  unsigned ua = __builtin_bit_cast(unsigned, a) + 0x8000u;
  unsigned ub = __builtin_bit_cast(unsigned, b) + 0x8000u;
#if __has_builtin(__builtin_amdgcn_perm)
  return __builtin_amdgcn_perm(ub, ua, 0x07060302u);
#else
  return (ub & 0xffff0000u) | (ua >> 16);
#endif
}

// ---------------------------------------------------------------------------
// 1) Weights -> fragment-group layout.
//    Chunk definition (all GEMMs): group g=(g16*2+kk), lane l'=(quad*16+lm),
//    8 shorts e: W^T[ntile_base + g16*16+lm][ks*64 + kk*32 + quad*8 + e].
//    BN256 matrices (Wq,Wk,Wv): panel (ct in 0..3, ks in 0..15) = 32 groups
//    at (ct*16+ks)*16384 shorts. BN128 (Wo): (ct in 0..7): 16 groups at
//    (ct*16+ks)*8192.
__global__ __launch_bounds__(256) void make_wgroups(
    const float* __restrict__ W0, const float* __restrict__ W1,
    const float* __restrict__ W2, const float* __restrict__ W3,
    short* __restrict__ G0, short* __restrict__ G1,
    short* __restrict__ G2, short* __restrict__ G3) {
  __shared__ float tile[64][68];  // [k][n], padded
  const int m = blockIdx.z;
  const float* W = m == 0 ? W0 : m == 1 ? W1 : m == 2 ? W2 : W3;
  short*       G = m == 0 ? G0 : m == 1 ? G1 : m == 2 ? G2 : G3;
  const int nt = blockIdx.x, kt = blockIdx.y;  // 16 x 16 tiles of 64x64
  const int n0 = nt * 64, k0 = kt * 64;
  const int t = threadIdx.x;
  for (int j = 0; j < 4; j++) {
    int idx = j * 256 + t, r = idx >> 4, cq = idx & 15;
    *(floatx4*)&tile[r][cq * 4] = *(const floatx4*)(W + (long)(k0 + r) * DM + n0 + cq * 4);
  }
  __syncthreads();
  for (int j = 0; j < 2; j++) {
    int ci = j * 256 + t;
    int lm = ci & 15, quad = (ci >> 4) & 3, kk = (ci >> 6) & 1, gl = ci >> 7;
    s16x8 v;
#pragma unroll
    for (int e = 0; e < 8; e++) v[e] = f2bf(tile[kk * 32 + quad * 8 + e][gl * 16 + lm]);
    long addr;
    if (m < 3) {
      int ct = nt >> 2, g16 = (nt & 3) * 4 + gl;
      addr = ((long)(ct * 16 + kt)) * 16384 + (g16 * 2 + kk) * 512 + (quad * 16 + lm) * 8;
    } else {
      int ct = nt >> 1, g16 = (nt & 1) * 4 + gl;
      addr = ((long)(ct * 16 + kt)) * 8192 + (g16 * 2 + kk) * 512 + (quad * 16 + lm) * 8;
    }
    *(s16x8*)(G + addr) = v;
  }
}

// ---------------------------------------------------------------------------
// 2) Projection GEMM: C[8192x1024] = A(fp32) @ W.  128x256 tile, BK=64, 512thr.
//    Per 48KiB buffer: A bf16 16 groups x 1KiB (g16*2+kk) at byte g*1024,
//    swizzled slot l''' = quad*16 + (lm ^ (quad*2)); B bf16 32 groups at byte
//    16384 + gb*1024, linear. z=0:->Qh (PRE-SCALED log2e/sqrt(1024)),
//    z=1: K->KVg groups 0..15, z=2: V->KVg groups 16..31 (interleaved keys).
__global__ __launch_bounds__(512, 2) void proj_kernel(
    const float* __restrict__ Aq, const float* __restrict__ Ak, const float* __restrict__ Av,
    const short* __restrict__ BgQ, const short* __restrict__ BgK, const short* __restrict__ BgV,
    short* __restrict__ Qh, short* __restrict__ KVg) {
  __shared__ short lds[2 * 24576];  // 2 x 48 KiB
  const int z = blockIdx.z;
  const float* A  = z == 0 ? Aq  : z == 1 ? Ak  : Av;
  const short* Bg = z == 0 ? BgQ : z == 1 ? BgK : BgV;
  const int t = threadIdx.x;
  const int w = t >> 6, l = t & 63, quad = l >> 4, lm = l & 15;
  const int wm = w >> 2, wn = w & 3;  // 2 row-waves x 4 col-waves
  const int row0 = blockIdx.x * 128;
  const int ct = blockIdx.y;          // 256-col tile
  const int col0 = ct * 256;

  floatx4 acc[4][4];
  for (int mi = 0; mi < 4; mi++)
    for (int ni = 0; ni < 4; ni++) acc[mi][ni] = (floatx4){0.f, 0.f, 0.f, 0.f};

  // A reg-stage: thread covers chunks tt = j*512+t (j=0,1): row r=tt>>3 (0..127),
  // 8 floats at (tt&7)*8 -- 8 lanes/row = 256B coalesced runs.
  floatx4 ar[2][2];
  auto loadA = [&](int ks) __attribute__((always_inline)) {
#pragma unroll
    for (int j = 0; j < 2; j++) {
      int tt = j * 512 + t, r = tt >> 3, c8 = (tt & 7) * 8;
      const float* p = A + (long)(row0 + r) * DM + ks * 64 + c8;
      ar[j][0] = *(const floatx4*)p;
      ar[j][1] = *(const floatx4*)(p + 4);
    }
  };
  auto writeA = [&](int buf) __attribute__((always_inline)) {
#pragma unroll
    for (int j = 0; j < 2; j++) {
      int tt = j * 512 + t, r = tt >> 3;
      int kk = (tt & 7) >> 2, q4 = tt & 3, lm2 = r & 15, g16 = r >> 4;
      u32x4 pk = {cvtpk_bf16(ar[j][0][0], ar[j][0][1]), cvtpk_bf16(ar[j][0][2], ar[j][0][3]),
                  cvtpk_bf16(ar[j][1][0], ar[j][1][1]), cvtpk_bf16(ar[j][1][2], ar[j][1][3])};
      int l3 = q4 * 16 + (lm2 ^ (q4 * 2));  // XOR swizzle: 2-way max write/read
      *(s16x8*)(lds + buf * 24576 + (g16 * 2 + kk) * 512 + l3 * 8) =
          __builtin_bit_cast(s16x8, pk);
    }
  };
  auto stageB = [&](int ks, int buf) __attribute__((always_inline)) {
#pragma unroll
    for (int i = 0; i < 4; i++) {
      int gb = w * 4 + i;
      const short* src = Bg + ((long)(ct * 16 + ks)) * 16384 + gb * 512 + l * 8;
      gload_lds16(src, lds + buf * 24576 + 8192 + gb * 512);
    }
  };

  const unsigned lds0 = lds_addr(lds);
  auto process = [&](int buf) __attribute__((always_inline)) {
    const unsigned lbase = lds0 + buf * 49152;
    const unsigned aswz = (quad * 16 + (lm ^ (quad * 2))) * 16;
#pragma unroll
    for (int kk = 0; kk < 2; kk++) {
      s16x8 af[4], bfr[4];
#pragma unroll
      for (int mi = 0; mi < 4; mi++)
        af[mi] = ds_read_b128a(lbase + ((wm * 4 + mi) * 2 + kk) * 1024 + aswz);
#pragma unroll
      for (int ni = 0; ni < 4; ni++)
        bfr[ni] = ds_read_b128a(lbase + 16384 + ((wn * 4 + ni) * 2 + kk) * 1024 + l * 16);
      WAIT_LGKM0();
      __builtin_amdgcn_s_setprio(1);
#pragma unroll
      for (int mi = 0; mi < 4; mi++)
#pragma unroll
        for (int ni = 0; ni < 4; ni++)
          acc[mi][ni] = mfma_bf16(af[mi], bfr[ni], acc[mi][ni]);
      __builtin_amdgcn_s_setprio(0);
    }
  };

  loadA(0);
  stageB(0, 0);
  writeA(0);
  __syncthreads();
  int cur = 0;
  for (int ks = 0; ks < 16; ++ks) {
    if (ks + 1 < 16) { loadA(ks + 1); stageB(ks + 1, cur ^ 1); }
    __builtin_amdgcn_sched_barrier(0);
    process(cur);
    if (ks + 1 < 16) writeA(cur ^ 1);  // A regs landed under process (vmcnt)
    __syncthreads();                   // drains B glds (issued ~process ago)
    cur ^= 1;
  }

  const int rowbase = row0 + wm * 64;
  const int colbase = col0 + wn * 64;
  const int b = rowbase >> 11;
  const int h = colbase >> 6;
  const int rloc = rowbase & 2047;
  if (z == 0) {
    const float osc = 0.0450842200277801f;  // log2(e)/sqrt(1024)
    long base = ((long)(b * HEADS + h)) * NSEQ * HD;
    for (int mi = 0; mi < 4; mi++)
      for (int r = 0; r < 4; r++) {
        int q = rloc + mi * 16 + quad * 4 + r;
        long rowoff = base + (long)q * HD + lm;
        for (int ni = 0; ni < 4; ni++)
          Qh[rowoff + ni * 16] = f2bf(acc[mi][ni][r] * osc);
      }
  } else if (z == 1) {
    // K chunks: group s*4+j*2+c, lane quadk*16+lmk, elem ek.
    long bhb = ((long)(b * HEADS + h)) * 262144;
    for (int mi = 0; mi < 4; mi++)
      for (int r = 0; r < 4; r++) {
        int q = rloc + mi * 16 + quad * 4 + r;
        int tile = q >> 7, s = (q >> 5) & 3, jj = (q >> 4) & 1, lmk = q & 15;
        for (int ni = 0; ni < 4; ni++) {
          int c = ni >> 1, quadk = (ni * 2 + (lm >> 3)) & 3, ek = lm & 7;
          long addr = bhb + (long)tile * 16384 + (s * 4 + jj * 2 + c) * 512 +
                      (quadk * 16 + lmk) * 8 + ek;
          KVg[addr] = f2bf(acc[mi][ni][r]);
        }
      }
  } else {
    // V chunks (interleaved keys): group 16+s*4+ni, lane quad*16+lm, elem ev.
    long bhb = ((long)(b * HEADS + h)) * 262144;
    for (int mi = 0; mi < 4; mi++)
      for (int r = 0; r < 4; r++) {
        int kc = rloc + (mi >> 1) * 32 + quad * 8 + (mi & 1) * 4 + r;
        int tile = kc >> 7, s = (kc >> 5) & 3, ev = (mi & 1) * 4 + r;
        for (int ni = 0; ni < 4; ni++) {
          long addr = bhb + (long)tile * 16384 + (16 + s * 4 + ni) * 512 +
                      (quad * 16 + lm) * 8 + ev;
          KVg[addr] = f2bf(acc[mi][ni][r]);
        }
      }
  }
}

// ---------------------------------------------------------------------------
// 3) Transposed-S flash attention. Grid (bh=64, qy=16) -> XCD = bh%8.
//    4 waves, wave = 32 q-rows; 128-key tiles staged from KVg with CONTIGUOUS
//    1KB gload_lds (8/wave/tile); consumer/process identical to R13.
__global__ __launch_bounds__(256, 2) void attn_kernel(
    const short* __restrict__ Qh, const short* __restrict__ KVg,
    short* __restrict__ Obf) {
  __shared__ short lds[2 * 16384];
  const int t = threadIdx.x;
  const int w = t >> 6, l = t & 63, quad = l >> 4, lm = l & 15;
  const int bh = blockIdx.x;
  const int qtile = blockIdx.y * 128 + w * 32;
  const short* Qp  = Qh  + (long)bh * NSEQ * HD;
  const short* KVp = KVg + (long)bh * 262144;

  s16x8 aq[2][2];
#pragma unroll
  for (int qi = 0; qi < 2; qi++)
#pragma unroll
    for (int c = 0; c < 2; c++)
      aq[qi][c] = *(const s16x8*)(Qp + (long)(qtile + qi * 16 + lm) * HD + c * 32 + quad * 8);

  floatx4 acc[2][4];
  float lsum[2] = {0.f, 0.f};
#pragma unroll
  for (int qi = 0; qi < 2; qi++)
#pragma unroll
    for (int n = 0; n < 4; n++) acc[qi][n] = (floatx4){0.f, 0.f, 0.f, 0.f};

  auto stage = [&](int kt, int buf) __attribute__((always_inline)) {
    short* base = lds + buf * 16384;
    const short* tsrc = KVp + (long)(kt >> 7) * 16384;
#pragma unroll
    for (int i = 0; i < 8; i++) {
      int g = w * 8 + i;
      gload_lds16(tsrc + g * 512 + l * 8, base + g * 512);  // contiguous 1KB
    }
  };

  auto process = [&](const short* Lb, int s) __attribute__((always_inline)) {
    s16x8 bk[2][2];
#pragma unroll
    for (int j = 0; j < 2; j++)
#pragma unroll
      for (int c = 0; c < 2; c++)
        bk[j][c] = *(const s16x8*)(Lb + ((s * 4 + j * 2 + c) * 64 + l) * 8);
    s16x8 vraw[4];
#pragma unroll
    for (int n = 0; n < 4; n++)
      vraw[n] = *(const s16x8*)(Lb + ((16 + s * 4 + n) * 64 + l) * 8);
#pragma unroll
    for (int qi = 0; qi < 2; qi++) {
      floatx4 sT[2];
      sT[0] = (floatx4){0.f, 0.f, 0.f, 0.f};
      sT[1] = (floatx4){0.f, 0.f, 0.f, 0.f};
      __builtin_amdgcn_s_setprio(1);
#pragma unroll
      for (int c = 0; c < 2; c++) {
        sT[0] = mfma_bf16(bk[0][c], aq[qi][c], sT[0]);
        sT[1] = mfma_bf16(bk[1][c], aq[qi][c], sT[1]);
      }
      __builtin_amdgcn_s_setprio(0);
      float p0 = __builtin_amdgcn_exp2f(sT[0][0]);
      float p1 = __builtin_amdgcn_exp2f(sT[0][1]);
      float p2 = __builtin_amdgcn_exp2f(sT[0][2]);
      float p3 = __builtin_amdgcn_exp2f(sT[0][3]);
      float p4 = __builtin_amdgcn_exp2f(sT[1][0]);
      float p5 = __builtin_amdgcn_exp2f(sT[1][1]);
      float p6 = __builtin_amdgcn_exp2f(sT[1][2]);
      float p7 = __builtin_amdgcn_exp2f(sT[1][3]);
      lsum[qi] += ((p0 + p1) + (p2 + p3)) + ((p4 + p5) + (p6 + p7));
      u32x4 pw = {pack2_bf16(p0, p1), pack2_bf16(p2, p3),
                  pack2_bf16(p4, p5), pack2_bf16(p6, p7)};
      s16x8 pcat = __builtin_bit_cast(s16x8, pw);
      __builtin_amdgcn_s_setprio(1);
#pragma unroll
      for (int n = 0; n < 4; n++)
        acc[qi][n] = mfma_bf16(vraw[n], pcat, acc[qi][n]);
      __builtin_amdgcn_s_setprio(0);
    }
  };

  stage(0, 0);
  __syncthreads();
  int cur = 0;
  for (int kt = 0; kt < NSEQ; kt += 128) {
    if (kt + 128 < NSEQ) stage(kt + 128, cur ^ 1);
    const short* Lb = lds + cur * 16384;
    process(Lb, 0);
    process(Lb, 1);
    process(Lb, 2);
    process(Lb, 3);
    __syncthreads();
    cur ^= 1;
  }

  const int b = bh >> 4, h = bh & 15;
  short* Ow = lds + w * 1152;  // buf0 region; final tile was read from buf1
  const int erow = l >> 2, ecg = l & 3;
#pragma unroll
  for (int qi = 0; qi < 2; qi++) {
    float ls = lsum[qi];
    ls += __shfl_xor(ls, 16);
    ls += __shfl_xor(ls, 32);
    float rl = 1.0f / ls;
#pragma unroll
    for (int n = 0; n < 4; n++)
#pragma unroll
      for (int r = 0; r < 4; r++)
        Ow[lm * 72 + n * 16 + quad * 4 + r] = f2bf(acc[qi][n][r] * rl);
    s16x8 o0 = *(const s16x8*)(Ow + erow * 72 + ecg * 16);
    s16x8 o1 = *(const s16x8*)(Ow + erow * 72 + ecg * 16 + 8);
    long gaddr = ((long)(b * NSEQ + qtile + qi * 16 + erow)) * DM + h * HD + ecg * 16;
    *(s16x8*)(Obf + gaddr) = o0;
    *(s16x8*)(Obf + gaddr + 8) = o1;
  }
}

// ---------------------------------------------------------------------------
// 4) Output GEMM: d_out = Obf(bf16) @ Wo + bo. 128x128, BK=64.
//    A reg-staged coalesced (128B row-runs) -> swizzled ds_write_b128;
//    B contiguous gload_lds from WoG group layout.
__global__ __launch_bounds__(256, 2) void out_kernel(
    const short* __restrict__ Ab, const short* __restrict__ WoG,
    const float* __restrict__ bias, float* __restrict__ Out) {
  __shared__ short lds[2 * 16384];  // 2 x 32 KiB (A 16K + B 16K)
  const int t = threadIdx.x;
  const int w = t >> 6, l = t & 63, quad = l >> 4, lm = l & 15;
  const int wm = w >> 1, wn = w & 1;
  const int row0 = blockIdx.x * 128;
  const int ct = blockIdx.y;
  const int col0 = ct * 128;

  floatx4 acc[4][4];
  for (int mi = 0; mi < 4; mi++)
    for (int ni = 0; ni < 4; ni++) acc[mi][ni] = (floatx4){0.f, 0.f, 0.f, 0.f};

  s16x8 ar[4];
  auto loadA = [&](int ks) __attribute__((always_inline)) {
#pragma unroll
    for (int j = 0; j < 4; j++) {
      int tt = j * 256 + t, r = tt >> 3, c = tt & 7;
      ar[j] = *(const s16x8*)(Ab + (long)(row0 + r) * DM + ks * 64 + c * 8);
    }
  };
  auto writeA = [&](int buf) __attribute__((always_inline)) {
#pragma unroll
    for (int j = 0; j < 4; j++) {
      int tt = j * 256 + t, r = tt >> 3, c = tt & 7;
      int kk = c >> 2, q4 = c & 3, lm2 = r & 15, g16 = r >> 4;
      int l3 = q4 * 16 + (lm2 ^ (q4 * 2));
      *(s16x8*)(lds + buf * 16384 + (g16 * 2 + kk) * 512 + l3 * 8) = ar[j];
    }
  };
  auto stageB = [&](int ks, int buf) __attribute__((always_inline)) {
#pragma unroll
    for (int i = 0; i < 4; i++) {
      int gb = w * 4 + i;
      const short* src = WoG + ((long)(ct * 16 + ks)) * 8192 + gb * 512 + l * 8;
      gload_lds16(src, lds + buf * 16384 + 8192 + gb * 512);
    }
  };
  const unsigned lds0 = lds_addr(lds);
  auto process = [&](int buf) __attribute__((always_inline)) {
    const unsigned lbase = lds0 + buf * 32768;
    const unsigned aswz = (quad * 16 + (lm ^ (quad * 2))) * 16;
#pragma unroll
    for (int kk = 0; kk < 2; kk++) {
      s16x8 af[4], bfr[4];
#pragma unroll
      for (int mi = 0; mi < 4; mi++)
        af[mi] = ds_read_b128a(lbase + ((wm * 4 + mi) * 2 + kk) * 1024 + aswz);
#pragma unroll
      for (int ni = 0; ni < 4; ni++)
        bfr[ni] = ds_read_b128a(lbase + 16384 + ((wn * 4 + ni) * 2 + kk) * 1024 + l * 16);
      WAIT_LGKM0();
      __builtin_amdgcn_s_setprio(1);
#pragma unroll
      for (int mi = 0; mi < 4; mi++)
#pragma unroll
        for (int ni = 0; ni < 4; ni++)
          acc[mi][ni] = mfma_bf16(af[mi], bfr[ni], acc[mi][ni]);
      __builtin_amdgcn_s_setprio(0);
    }
  };

  loadA(0);
  stageB(0, 0);
  writeA(0);
  __syncthreads();
  int cur = 0;
  for (int ks = 0; ks < 16; ++ks) {
    if (ks + 1 < 16) { loadA(ks + 1); stageB(ks + 1, cur ^ 1); }
    __builtin_amdgcn_sched_barrier(0);
    process(cur);
    if (ks + 1 < 16) writeA(cur ^ 1);
    __syncthreads();
    cur ^= 1;
  }

  const int rowbase = row0 + wm * 64;
  const int colbase = col0 + wn * 64;
  for (int mi = 0; mi < 4; mi++)
    for (int r = 0; r < 4; r++) {
      int gr = rowbase + mi * 16 + quad * 4 + r;
      for (int ni = 0; ni < 4; ni++) {
        int gc = colbase + ni * 16 + lm;
        Out[(long)gr * DM + gc] = acc[mi][ni][r] + bias[gc];
      }
    }
}

// ---------------------------------------------------------------------------
extern "C" void kernel_launch(void* const* d_in, const int* in_sizes, int n_in,
                              void* d_out, int out_size, void* d_ws, size_t ws_size,
                              hipStream_t stream) {
  (void)in_sizes; (void)n_in; (void)out_size; (void)ws_size;
  const float* queries = (const float*)d_in[0];
  const float* keys    = (const float*)d_in[1];
  const float* values  = (const float*)d_in[2];
  const float* Wq = (const float*)d_in[3];
  const float* Wk = (const float*)d_in[4];
  const float* Wv = (const float*)d_in[5];
  const float* Wo = (const float*)d_in[6];
  const float* bo = (const float*)d_in[7];
  float* out = (float*)d_out;

  char* ws = (char*)d_ws;
  const size_t MB = 1024 * 1024;
  short* WqG = (short*)(ws + 0 * MB);   // 2 MiB each (group layout)
  short* WkG = (short*)(ws + 2 * MB);
  short* WvG = (short*)(ws + 4 * MB);
  short* WoG = (short*)(ws + 6 * MB);
  short* Qh  = (short*)(ws + 8 * MB);   // [B,H,2048,64] bf16 = 16 MiB
  short* KVg = (short*)(ws + 24 * MB);  // [bh][16 tiles][32 groups][64][8] = 32 MiB
  short* Obf = (short*)(ws + 56 * MB);  // [8192,1024] bf16 = 16 MiB (total 72)

  make_wgroups<<<dim3(16, 16, 4), 256, 0, stream>>>(
      Wq, Wk, Wv, Wo, WqG, WkG, WvG, WoG);
  proj_kernel<<<dim3(64, 4, 3), 512, 0, stream>>>(
      queries, keys, values, WqG, WkG, WvG, Qh, KVg);
  attn_kernel<<<dim3(64, 16), 256, 0, stream>>>(Qh, KVg, Obf);
  out_kernel<<<dim3(64, 8), 256, 0, stream>>>(Obf, WoG, bo, out);
}